// Round 1
// 409.331 us; speedup vs baseline: 1.0057x; 1.0057x over previous
//
#include <hip/hip_runtime.h>

#define NN 100000
#define NE 1600000
#define NBK 782   // ceil(NN/128) 128-node buckets
#define NBLK 256  // persistent blocks for counting sort
#define CHUNK ((NE + NBLK - 1) / NBLK)  // 6250

typedef __bf16 bf16x2 __attribute__((ext_vector_type(2)));
typedef __bf16 bf16x4 __attribute__((ext_vector_type(4)));
typedef __bf16 bf16x8 __attribute__((ext_vector_type(8)));
typedef float f32x4 __attribute__((ext_vector_type(4)));

// ---------------- W pre-transpose: Wt[n][k] = (bf16)W[k][n], all 3 layers ----------------

__global__ __launch_bounds__(256) void kW_prep(const float* __restrict__ W0, const float* __restrict__ W1,
                                               const float* __restrict__ W2, __bf16* __restrict__ Wt) {
  int i = blockIdx.x * 256 + threadIdx.x;  // 40960 total
  if (i < 16384) {        // W0 128x128, i = k*128+n
    int k = i >> 7, n = i & 127;
    Wt[n * 128 + k] = (__bf16)W0[i];
  } else if (i < 32768) { // W1 128x128
    int j = i - 16384;
    int k = j >> 7, n = j & 127;
    Wt[16384 + n * 128 + k] = (__bf16)W1[j];
  } else if (i < 40960) { // W2 128x64, j = k*64+n
    int j = i - 32768;
    int k = j >> 6, n = j & 63;
    Wt[32768 + n * 128 + k] = (__bf16)W2[j];
  }
}

// ---------------- privatized counting sort by dst-bucket ----------------

__global__ __launch_bounds__(256) void k1_hist(const int* __restrict__ dst, int* __restrict__ bhist) {
  __shared__ int h[NBK];
  int tid = threadIdx.x, b = blockIdx.x;
  for (int i = tid; i < NBK; i += 256) h[i] = 0;
  __syncthreads();
  int base = b * CHUNK, end = min(base + CHUNK, NE);
  for (int e = base + tid; e < end; e += 256) atomicAdd(&h[dst[e] >> 7], 1);
  __syncthreads();
  for (int i = tid; i < NBK; i += 256) bhist[i * NBLK + b] = h[i];
}

__global__ __launch_bounds__(256) void kA2(const int* __restrict__ bhist, int* __restrict__ btot) {
  int w = threadIdx.x >> 6, lane = threadIdx.x & 63;
  int bin = blockIdx.x * 4 + w;
  if (bin >= NBK) return;
  int4 v = *(const int4*)(bhist + bin * NBLK + lane * 4);
  int s = v.x + v.y + v.z + v.w;
#pragma unroll
  for (int off = 32; off > 0; off >>= 1) s += __shfl_xor(s, off);
  if (lane == 0) btot[bin] = s;
}

__global__ __launch_bounds__(1024) void kB_bscan(const int* __restrict__ btot, int* __restrict__ bptr) {
  __shared__ int s[1024];
  int tid = threadIdx.x;
  int v = (tid < NBK) ? btot[tid] : 0;
  s[tid] = v;
  __syncthreads();
  for (int off = 1; off < 1024; off <<= 1) {
    int t = (tid >= off) ? s[tid - off] : 0;
    __syncthreads();
    s[tid] += t;
    __syncthreads();
  }
  if (tid < NBK) bptr[tid + 1] = s[tid];
  if (tid == 0) bptr[0] = 0;
}

__global__ __launch_bounds__(256) void kC2(const int* __restrict__ bhist, const int* __restrict__ bptr,
                                           int* __restrict__ blockbase) {
  int w = threadIdx.x >> 6, lane = threadIdx.x & 63;
  int bin = blockIdx.x * 4 + w;
  if (bin >= NBK) return;
  int4 v = *(const int4*)(bhist + bin * NBLK + lane * 4);
  int ls = v.x + v.y + v.z + v.w;
  int incl = ls;
#pragma unroll
  for (int off = 1; off < 64; off <<= 1) {
    int t = __shfl_up(incl, off);
    if (lane >= off) incl += t;
  }
  int base = bptr[bin] + incl - ls;
  int4 o;
  o.x = base;
  o.y = base + v.x;
  o.z = base + v.x + v.y;
  o.w = base + v.x + v.y + v.z;
  *(int4*)(blockbase + bin * NBLK + lane * 4) = o;
}

__global__ __launch_bounds__(256) void k3_scatter(const int* __restrict__ src, const int* __restrict__ dst,
                                                  const int* __restrict__ blockbase, int* __restrict__ bucketed) {
  __shared__ int cur[NBK];
  int tid = threadIdx.x, b = blockIdx.x;
  for (int i = tid; i < NBK; i += 256) cur[i] = blockbase[i * NBLK + b];
  __syncthreads();
  int base = b * CHUNK, end = min(base + CHUNK, NE);
  for (int e = base + tid; e < end; e += 256) {
    int d = dst[e];
    int pos = atomicAdd(&cur[d >> 7], 1);
    bucketed[pos] = (src[e] << 7) | (d & 127);
  }
}

__global__ __launch_bounds__(256) void k_degfill(const int* __restrict__ bucketed, const int* __restrict__ bptr,
                                                 int* __restrict__ row_ptr, float* __restrict__ dis,
                                                 int* __restrict__ csr_src) {
  __shared__ int deg[128];
  __shared__ int sc[128];
  __shared__ int cur[128];
  int b = blockIdx.x, tid = threadIdx.x;
  int nb0 = b << 7;
  if (tid < 128) deg[tid] = 0;
  __syncthreads();
  int beg = bptr[b], end = bptr[b + 1];
  for (int e = beg + tid; e < end; e += 256) atomicAdd(&deg[bucketed[e] & 127], 1);
  __syncthreads();
  if (tid < 128) sc[tid] = deg[tid];
  __syncthreads();
  for (int off = 1; off < 128; off <<= 1) {
    int t = (tid >= off && tid < 128) ? sc[tid - off] : 0;
    __syncthreads();
    if (tid < 128) sc[tid] += t;
    __syncthreads();
  }
  if (tid < 128) {
    cur[tid] = beg + sc[tid] - deg[tid];
    if (nb0 + tid < NN) {
      row_ptr[nb0 + tid + 1] = beg + sc[tid];
      dis[nb0 + tid] = rsqrtf((float)(deg[tid] + 1));
      if (b == 0 && tid == 0) row_ptr[0] = 0;
    }
  }
  __syncthreads();
  for (int e = beg + tid; e < end; e += 256) {
    int pk = bucketed[e];
    int pos = atomicAdd(&cur[pk & 127], 1);
    csr_src[pos] = pk >> 7;
  }
}

// ---------------- bf16 MFMA GEMM, direct-A-load variant ----------------

template <int BN, int MODE>
__global__ __launch_bounds__(256) void k_gemm(const void* __restrict__ Av, const __bf16* __restrict__ Wt,
                                              const float* __restrict__ bias, const float* __restrict__ dis,
                                              __bf16* __restrict__ out) {
  constexpr int LDK = 136;  // 128 + 8 pad: row stride 272 B -> 4-bank rotation
  constexpr int NT = BN / 32;
  __shared__ __bf16 lB[BN * LDK];

  const int tid = threadIdx.x;
  const int rowBase = blockIdx.x * 128;
  const int lane = tid & 63;
  const int wid = tid >> 6;
  const int wm = (wid & 1) * 64;
  const int wn = (wid >> 1) * (BN / 2);
  const int lm = lane & 15;
  const int kg = lane >> 4;

  for (int c = tid; c < 16 * BN; c += 256) {
    int n = c >> 4;
    int koff = (c & 15) * 8;
    bf16x8 w = *(const bf16x8*)(Wt + n * 128 + koff);
    *(bf16x8*)&lB[n * LDK + koff] = w;
  }
  __syncthreads();

  f32x4 acc[4][NT] = {};
  const bool full = (rowBase + 128 <= NN);

#pragma unroll 2
  for (int ks = 0; ks < 128; ks += 32) {
    int k0 = ks + kg * 8;
    bf16x8 af[4];
    if constexpr (MODE == 0) {
      const float* A = (const float*)Av;
#pragma unroll
      for (int tm = 0; tm < 4; ++tm) {
        int gr = rowBase + wm + tm * 16 + lm;
        f32x4 a0 = {}, a1 = {};
        if (full || gr < NN) {
          a0 = *(const f32x4*)(A + (size_t)gr * 128 + k0);
          a1 = *(const f32x4*)(A + (size_t)gr * 128 + k0 + 4);
        }
        af[tm] = bf16x8{(__bf16)a0[0], (__bf16)a0[1], (__bf16)a0[2], (__bf16)a0[3],
                        (__bf16)a1[0], (__bf16)a1[1], (__bf16)a1[2], (__bf16)a1[3]};
      }
    } else {
      const __bf16* A = (const __bf16*)Av;
      f32x4 b0 = *(const f32x4*)(bias + k0);
      f32x4 b1 = *(const f32x4*)(bias + k0 + 4);
#pragma unroll
      for (int tm = 0; tm < 4; ++tm) {
        int gr = rowBase + wm + tm * 16 + lm;
        bf16x8 v = {};
        if (full || gr < NN) v = *(const bf16x8*)(A + (size_t)gr * 128 + k0);
        af[tm] = bf16x8{(__bf16)fmaxf((float)v[0] + b0[0], 0.f), (__bf16)fmaxf((float)v[1] + b0[1], 0.f),
                        (__bf16)fmaxf((float)v[2] + b0[2], 0.f), (__bf16)fmaxf((float)v[3] + b0[3], 0.f),
                        (__bf16)fmaxf((float)v[4] + b1[0], 0.f), (__bf16)fmaxf((float)v[5] + b1[1], 0.f),
                        (__bf16)fmaxf((float)v[6] + b1[2], 0.f), (__bf16)fmaxf((float)v[7] + b1[3], 0.f)};
      }
    }
    bf16x8 bfr[NT];
#pragma unroll
    for (int tn = 0; tn < NT; ++tn)
      bfr[tn] = *(const bf16x8*)&lB[(wn + tn * 16 + lm) * LDK + k0];
#pragma unroll
    for (int tm = 0; tm < 4; ++tm)
#pragma unroll
      for (int tn = 0; tn < NT; ++tn)
        acc[tm][tn] = __builtin_amdgcn_mfma_f32_16x16x32_bf16(af[tm], bfr[tn], acc[tm][tn], 0, 0, 0);
  }

#pragma unroll
  for (int tm = 0; tm < 4; ++tm) {
    int r0 = rowBase + wm + tm * 16 + kg * 4;
#pragma unroll
    for (int tn = 0; tn < NT; ++tn) {
      int c0 = wn + tn * 16 + lm;
#pragma unroll
      for (int r = 0; r < 4; ++r) {
        int gr = r0 + r;
        if (full || gr < NN) out[(size_t)gr * BN + c0] = (__bf16)(acc[tm][tn][r] * dis[gr]);
      }
    }
  }
}

// ---------------- grouped pull aggregation (F=128) ----------------
// Restructured: every node's gather completes in ONE parallel masked round
// (4 loads for deg<=16, 8 loads for deg<=32; Poisson(16) => P(deg>32)~3e-5).
// Out-of-range lanes gather row 0 (valid, hot in cache) and are zeroed via a
// branch-free {0,1} multiplier (cndmask+fma, same VALU rate as the plain add).
// Old code serialized deg<16 / 17..32 nodes into 2-4 dependent ~800cy rounds.

__global__ __launch_bounds__(256) void k_agg128(const __bf16* __restrict__ tmp, const int* __restrict__ row_ptr,
                                                const int* __restrict__ csr_src, const float* __restrict__ dis,
                                                __bf16* __restrict__ agg) {
  int wid = (blockIdx.x * 256 + threadIdx.x) >> 6;
  int lane = threadIdx.x & 63;
  if (wid >= NN) return;
  int grp = lane >> 4;   // 0..3
  int fl = lane & 15;    // features [fl*8, fl*8+8)

  int beg = row_ptr[wid];
  int end = row_ptr[wid + 1];

  float acc[8];
  {
    bf16x8 sv = {};
    if (grp == 0) sv = *(const bf16x8*)&tmp[(size_t)wid * 128 + fl * 8];
#pragma unroll
    for (int t = 0; t < 8; ++t) acc[t] = (grp == 0) ? (float)sv[t] : 0.f;
  }

  for (int base = beg; base < end; base += 64) {
    int cnt = min(64, end - base);
    int sidx = (base + lane < end) ? csr_src[base + lane] : 0;
    int i = 0;
    while (i < cnt) {
      int rem = cnt - i;                  // wave-uniform branch
      if (rem > 16) {                     // one masked round of 32 edges: 8 loads in flight
        bf16x8 v[8];
#pragma unroll
        for (int u = 0; u < 8; ++u) {
          int s = __shfl(sidx, (i + u * 4 + grp) & 63);
          v[u] = *(const bf16x8*)&tmp[(size_t)s * 128 + fl * 8];
        }
#pragma unroll
        for (int u = 0; u < 8; ++u) {
          float m = (i + u * 4 + grp < cnt) ? 1.f : 0.f;
#pragma unroll
          for (int t = 0; t < 8; ++t) acc[t] += m * (float)v[u][t];
        }
        i += 32;
      } else {                            // one masked round of <=16 edges: 4 loads in flight
        bf16x8 v[4];
#pragma unroll
        for (int u = 0; u < 4; ++u) {
          int s = __shfl(sidx, (i + u * 4 + grp) & 63);
          v[u] = *(const bf16x8*)&tmp[(size_t)s * 128 + fl * 8];
        }
#pragma unroll
        for (int u = 0; u < 4; ++u) {
          float m = (i + u * 4 + grp < cnt) ? 1.f : 0.f;
#pragma unroll
          for (int t = 0; t < 8; ++t) acc[t] += m * (float)v[u][t];
        }
        i += 16;
      }
    }
  }

#pragma unroll
  for (int t = 0; t < 8; ++t) acc[t] += __shfl_xor(acc[t], 16);
#pragma unroll
  for (int t = 0; t < 8; ++t) acc[t] += __shfl_xor(acc[t], 32);

  if (grp == 0) {
    float d = dis[wid];
    bf16x8 o;
#pragma unroll
    for (int t = 0; t < 8; ++t) o[t] = (__bf16)(acc[t] * d);
    *(bf16x8*)&agg[(size_t)wid * 128 + fl * 8] = o;
  }
}

// ---------------- F=64 grouped aggregation fused with bias+relu+log_softmax ----------------
// Same single-masked-round restructure: 2/4/8 loads cover 16/32/64 edges, so
// every chunk (deg<=64, i.e. all nodes) finishes in one parallel gather round.

__global__ __launch_bounds__(256) void k_agg64_final(const __bf16* __restrict__ tmp, const int* __restrict__ row_ptr,
                                                     const int* __restrict__ csr_src, const float* __restrict__ dis,
                                                     const float* __restrict__ b2, float* __restrict__ out) {
  int wid = (blockIdx.x * 256 + threadIdx.x) >> 6;
  int lane = threadIdx.x & 63;
  if (wid >= NN) return;
  int grp = lane >> 3;  // 0..7
  int fl = lane & 7;    // features [fl*8, fl*8+8)

  int beg = row_ptr[wid];
  int end = row_ptr[wid + 1];

  float acc[8];
  {
    bf16x8 sv = {};
    if (grp == 0) sv = *(const bf16x8*)&tmp[(size_t)wid * 64 + fl * 8];
#pragma unroll
    for (int t = 0; t < 8; ++t) acc[t] = (grp == 0) ? (float)sv[t] : 0.f;
  }

  for (int base = beg; base < end; base += 64) {
    int cnt = min(64, end - base);
    int sidx = (base + lane < end) ? csr_src[base + lane] : 0;
    int i = 0;
    while (i < cnt) {
      int rem = cnt - i;                  // wave-uniform
      if (rem > 32) {                     // 64 edges: 8 loads in flight
        bf16x8 v[8];
#pragma unroll
        for (int u = 0; u < 8; ++u) {
          int s = __shfl(sidx, (i + u * 8 + grp) & 63);
          v[u] = *(const bf16x8*)&tmp[(size_t)s * 64 + fl * 8];
        }
#pragma unroll
        for (int u = 0; u < 8; ++u) {
          float m = (i + u * 8 + grp < cnt) ? 1.f : 0.f;
#pragma unroll
          for (int t = 0; t < 8; ++t) acc[t] += m * (float)v[u][t];
        }
        i += 64;
      } else if (rem > 16) {              // 32 edges: 4 loads
        bf16x8 v[4];
#pragma unroll
        for (int u = 0; u < 4; ++u) {
          int s = __shfl(sidx, (i + u * 8 + grp) & 63);
          v[u] = *(const bf16x8*)&tmp[(size_t)s * 64 + fl * 8];
        }
#pragma unroll
        for (int u = 0; u < 4; ++u) {
          float m = (i + u * 8 + grp < cnt) ? 1.f : 0.f;
#pragma unroll
          for (int t = 0; t < 8; ++t) acc[t] += m * (float)v[u][t];
        }
        i += 32;
      } else {                            // <=16 edges: 2 loads
        bf16x8 v[2];
#pragma unroll
        for (int u = 0; u < 2; ++u) {
          int s = __shfl(sidx, (i + u * 8 + grp) & 63);
          v[u] = *(const bf16x8*)&tmp[(size_t)s * 64 + fl * 8];
        }
#pragma unroll
        for (int u = 0; u < 2; ++u) {
          float m = (i + u * 8 + grp < cnt) ? 1.f : 0.f;
#pragma unroll
          for (int t = 0; t < 8; ++t) acc[t] += m * (float)v[u][t];
        }
        i += 16;
      }
    }
  }

#pragma unroll
  for (int t = 0; t < 8; ++t) acc[t] += __shfl_xor(acc[t], 8);
#pragma unroll
  for (int t = 0; t < 8; ++t) acc[t] += __shfl_xor(acc[t], 16);
#pragma unroll
  for (int t = 0; t < 8; ++t) acc[t] += __shfl_xor(acc[t], 32);

  float d = dis[wid];
  float v[8], lm_ = -1e30f;
#pragma unroll
  for (int t = 0; t < 8; ++t) {
    v[t] = fmaxf(acc[t] * d + b2[fl * 8 + t], 0.f);
    lm_ = fmaxf(lm_, v[t]);
  }
#pragma unroll
  for (int off = 32; off > 0; off >>= 1) lm_ = fmaxf(lm_, __shfl_xor(lm_, off));
  float le = 0.f;
#pragma unroll
  for (int t = 0; t < 8; ++t) le += expf(v[t] - lm_);
#pragma unroll
  for (int off = 32; off > 0; off >>= 1) le += __shfl_xor(le, off);
  float logss = logf(le * 0.125f);
  if (grp == 0) {
    float4 o0 = make_float4(v[0] - lm_ - logss, v[1] - lm_ - logss, v[2] - lm_ - logss, v[3] - lm_ - logss);
    float4 o1 = make_float4(v[4] - lm_ - logss, v[5] - lm_ - logss, v[6] - lm_ - logss, v[7] - lm_ - logss);
    *(float4*)&out[(size_t)wid * 64 + fl * 8] = o0;
    *(float4*)&out[(size_t)wid * 64 + fl * 8 + 4] = o1;
  }
}

// ---------------- launch ----------------

extern "C" void kernel_launch(void* const* d_in, const int* in_sizes, int n_in,
                              void* d_out, int out_size, void* d_ws, size_t ws_size,
                              hipStream_t stream) {
  const float* x  = (const float*)d_in[0];
  const int*   ei = (const int*)d_in[1];
  const float* W0 = (const float*)d_in[2];
  const float* b0 = (const float*)d_in[3];
  const float* W1 = (const float*)d_in[4];
  const float* b1 = (const float*)d_in[5];
  const float* W2 = (const float*)d_in[6];
  const float* b2 = (const float*)d_in[7];
  const int* esrc = ei;
  const int* edst = ei + NE;

  char* p = (char*)d_ws;
  auto alloc = [&](size_t bytes) {
    char* q = p;
    p += (bytes + 255) & ~(size_t)255;
    return q;
  };
  float*  dis     = (float*)alloc((size_t)NN * 4);
  int*    row_ptr = (int*)alloc((size_t)(NN + 1) * 4);
  int*    btot    = (int*)alloc(NBK * 4);
  int*    bptr    = (int*)alloc((NBK + 1) * 4);
  __bf16* Wt      = (__bf16*)alloc(40960 * 2);              // 80 KB: Wt0|Wt1|Wt2
  int*    csr_src = (int*)alloc((size_t)NE * 4);            // 6.4 MB
  __bf16* tmp     = (__bf16*)alloc((size_t)NN * 128 * 2);   // 25.6 MB
  int*    bucketed  = (int*)tmp;                            // 6.4 MB alias (packed edges)
  int*    bhist     = csr_src;                              // 800 KB alias [bin][block]
  int*    blockbase = csr_src + NBLK * NBK;                 // 800 KB alias [bin][block]

  kW_prep<<<160, 256, 0, stream>>>(W0, W1, W2, Wt);
  k1_hist<<<NBLK, 256, 0, stream>>>(edst, bhist);
  kA2<<<(NBK + 3) / 4, 256, 0, stream>>>(bhist, btot);
  kB_bscan<<<1, 1024, 0, stream>>>(btot, bptr);
  kC2<<<(NBK + 3) / 4, 256, 0, stream>>>(bhist, bptr, blockbase);
  k3_scatter<<<NBLK, 256, 0, stream>>>(esrc, edst, blockbase, bucketed);
  k_degfill<<<NBK, 256, 0, stream>>>(bucketed, bptr, row_ptr, dis, csr_src);

  int gblocks = (NN + 127) / 128;  // 782
  int ablocks = (NN * 64 + 255) / 256;

  k_gemm<128, 0><<<gblocks, 256, 0, stream>>>(x, Wt, nullptr, dis, tmp);
  k_agg128<<<ablocks, 256, 0, stream>>>(tmp, row_ptr, csr_src, dis, (__bf16*)d_out);

  k_gemm<128, 2><<<gblocks, 256, 0, stream>>>(d_out, Wt + 16384, b0, dis, tmp);
  k_agg128<<<ablocks, 256, 0, stream>>>(tmp, row_ptr, csr_src, dis, (__bf16*)d_out);

  k_gemm<64, 2><<<gblocks, 256, 0, stream>>>(d_out, Wt + 32768, b1, dis, tmp);
  k_agg64_final<<<ablocks, 256, 0, stream>>>(tmp, row_ptr, csr_src, dis, b2, (float*)d_out);
}

// Round 2
// 381.990 us; speedup vs baseline: 1.0777x; 1.0716x over previous
//
#include <hip/hip_runtime.h>

#define NN 100000
#define NE 1600000
#define NBK 782   // ceil(NN/128) 128-node buckets
#define NBLK 256  // persistent blocks for counting sort
#define CHUNK ((NE + NBLK - 1) / NBLK)  // 6250

typedef __bf16 bf16x8 __attribute__((ext_vector_type(8)));
typedef float f32x2 __attribute__((ext_vector_type(2)));
typedef float f32x4 __attribute__((ext_vector_type(4)));

// dequant 8 fp8 (uint2) with mask-multiply accumulate into acc[8]
#define ACC8_FP8(vv, mm)                                                              \
  {                                                                                   \
    f32x2 p;                                                                          \
    p = __builtin_amdgcn_cvt_pk_f32_fp8((vv).x, 0); acc[0] += (mm) * p[0]; acc[1] += (mm) * p[1]; \
    p = __builtin_amdgcn_cvt_pk_f32_fp8((vv).x, 1); acc[2] += (mm) * p[0]; acc[3] += (mm) * p[1]; \
    p = __builtin_amdgcn_cvt_pk_f32_fp8((vv).y, 0); acc[4] += (mm) * p[0]; acc[5] += (mm) * p[1]; \
    p = __builtin_amdgcn_cvt_pk_f32_fp8((vv).y, 1); acc[6] += (mm) * p[0]; acc[7] += (mm) * p[1]; \
  }

// ---------------- W pre-transpose: Wt[n][k] = (bf16)W[k][n], all 3 layers ----------------

__global__ __launch_bounds__(256) void kW_prep(const float* __restrict__ W0, const float* __restrict__ W1,
                                               const float* __restrict__ W2, __bf16* __restrict__ Wt) {
  int i = blockIdx.x * 256 + threadIdx.x;  // 40960 total
  if (i < 16384) {        // W0 128x128, i = k*128+n
    int k = i >> 7, n = i & 127;
    Wt[n * 128 + k] = (__bf16)W0[i];
  } else if (i < 32768) { // W1 128x128
    int j = i - 16384;
    int k = j >> 7, n = j & 127;
    Wt[16384 + n * 128 + k] = (__bf16)W1[j];
  } else if (i < 40960) { // W2 128x64, j = k*64+n
    int j = i - 32768;
    int k = j >> 6, n = j & 63;
    Wt[32768 + n * 128 + k] = (__bf16)W2[j];
  }
}

// ---------------- privatized counting sort by dst-bucket ----------------

__global__ __launch_bounds__(256) void k1_hist(const int* __restrict__ dst, int* __restrict__ bhist) {
  __shared__ int h[NBK];
  int tid = threadIdx.x, b = blockIdx.x;
  for (int i = tid; i < NBK; i += 256) h[i] = 0;
  __syncthreads();
  int base = b * CHUNK, end = min(base + CHUNK, NE);
  for (int e = base + tid; e < end; e += 256) atomicAdd(&h[dst[e] >> 7], 1);
  __syncthreads();
  for (int i = tid; i < NBK; i += 256) bhist[i * NBLK + b] = h[i];
}

__global__ __launch_bounds__(256) void kA2(const int* __restrict__ bhist, int* __restrict__ btot) {
  int w = threadIdx.x >> 6, lane = threadIdx.x & 63;
  int bin = blockIdx.x * 4 + w;
  if (bin >= NBK) return;
  int4 v = *(const int4*)(bhist + bin * NBLK + lane * 4);
  int s = v.x + v.y + v.z + v.w;
#pragma unroll
  for (int off = 32; off > 0; off >>= 1) s += __shfl_xor(s, off);
  if (lane == 0) btot[bin] = s;
}

__global__ __launch_bounds__(1024) void kB_bscan(const int* __restrict__ btot, int* __restrict__ bptr) {
  __shared__ int s[1024];
  int tid = threadIdx.x;
  int v = (tid < NBK) ? btot[tid] : 0;
  s[tid] = v;
  __syncthreads();
  for (int off = 1; off < 1024; off <<= 1) {
    int t = (tid >= off) ? s[tid - off] : 0;
    __syncthreads();
    s[tid] += t;
    __syncthreads();
  }
  if (tid < NBK) bptr[tid + 1] = s[tid];
  if (tid == 0) bptr[0] = 0;
}

__global__ __launch_bounds__(256) void kC2(const int* __restrict__ bhist, const int* __restrict__ bptr,
                                           int* __restrict__ blockbase) {
  int w = threadIdx.x >> 6, lane = threadIdx.x & 63;
  int bin = blockIdx.x * 4 + w;
  if (bin >= NBK) return;
  int4 v = *(const int4*)(bhist + bin * NBLK + lane * 4);
  int ls = v.x + v.y + v.z + v.w;
  int incl = ls;
#pragma unroll
  for (int off = 1; off < 64; off <<= 1) {
    int t = __shfl_up(incl, off);
    if (lane >= off) incl += t;
  }
  int base = bptr[bin] + incl - ls;
  int4 o;
  o.x = base;
  o.y = base + v.x;
  o.z = base + v.x + v.y;
  o.w = base + v.x + v.y + v.z;
  *(int4*)(blockbase + bin * NBLK + lane * 4) = o;
}

__global__ __launch_bounds__(256) void k3_scatter(const int* __restrict__ src, const int* __restrict__ dst,
                                                  const int* __restrict__ blockbase, int* __restrict__ bucketed) {
  __shared__ int cur[NBK];
  int tid = threadIdx.x, b = blockIdx.x;
  for (int i = tid; i < NBK; i += 256) cur[i] = blockbase[i * NBLK + b];
  __syncthreads();
  int base = b * CHUNK, end = min(base + CHUNK, NE);
  for (int e = base + tid; e < end; e += 256) {
    int d = dst[e];
    int pos = atomicAdd(&cur[d >> 7], 1);
    bucketed[pos] = (src[e] << 7) | (d & 127);
  }
}

__global__ __launch_bounds__(256) void k_degfill(const int* __restrict__ bucketed, const int* __restrict__ bptr,
                                                 int* __restrict__ row_ptr, float* __restrict__ dis,
                                                 int* __restrict__ csr_src) {
  __shared__ int deg[128];
  __shared__ int sc[128];
  __shared__ int cur[128];
  int b = blockIdx.x, tid = threadIdx.x;
  int nb0 = b << 7;
  if (tid < 128) deg[tid] = 0;
  __syncthreads();
  int beg = bptr[b], end = bptr[b + 1];
  for (int e = beg + tid; e < end; e += 256) atomicAdd(&deg[bucketed[e] & 127], 1);
  __syncthreads();
  if (tid < 128) sc[tid] = deg[tid];
  __syncthreads();
  for (int off = 1; off < 128; off <<= 1) {
    int t = (tid >= off && tid < 128) ? sc[tid - off] : 0;
    __syncthreads();
    if (tid < 128) sc[tid] += t;
    __syncthreads();
  }
  if (tid < 128) {
    cur[tid] = beg + sc[tid] - deg[tid];
    if (nb0 + tid < NN) {
      row_ptr[nb0 + tid + 1] = beg + sc[tid];
      dis[nb0 + tid] = rsqrtf((float)(deg[tid] + 1));
      if (b == 0 && tid == 0) row_ptr[0] = 0;
    }
  }
  __syncthreads();
  for (int e = beg + tid; e < end; e += 256) {
    int pk = bucketed[e];
    int pos = atomicAdd(&cur[pk & 127], 1);
    csr_src[pos] = pk >> 7;
  }
}

// ---------------- bf16 MFMA GEMM, direct-A-load variant ----------------
// OUT8=true: epilogue quantizes acc*dis to OCP fp8 e4m3 (1 B/elem) for the
// gather-bound aggregation that follows — halves the L2-miss gather floor.

template <int BN, int MODE, bool OUT8>
__global__ __launch_bounds__(256) void k_gemm(const void* __restrict__ Av, const __bf16* __restrict__ Wt,
                                              const float* __restrict__ bias, const float* __restrict__ dis,
                                              void* __restrict__ outv) {
  constexpr int LDK = 136;  // 128 + 8 pad: row stride 272 B -> 4-bank rotation
  constexpr int NT = BN / 32;
  __shared__ __bf16 lB[BN * LDK];

  const int tid = threadIdx.x;
  const int rowBase = blockIdx.x * 128;
  const int lane = tid & 63;
  const int wid = tid >> 6;
  const int wm = (wid & 1) * 64;
  const int wn = (wid >> 1) * (BN / 2);
  const int lm = lane & 15;
  const int kg = lane >> 4;

  for (int c = tid; c < 16 * BN; c += 256) {
    int n = c >> 4;
    int koff = (c & 15) * 8;
    bf16x8 w = *(const bf16x8*)(Wt + n * 128 + koff);
    *(bf16x8*)&lB[n * LDK + koff] = w;
  }
  __syncthreads();

  f32x4 acc[4][NT] = {};
  const bool full = (rowBase + 128 <= NN);

#pragma unroll 2
  for (int ks = 0; ks < 128; ks += 32) {
    int k0 = ks + kg * 8;
    bf16x8 af[4];
    if constexpr (MODE == 0) {
      const float* A = (const float*)Av;
#pragma unroll
      for (int tm = 0; tm < 4; ++tm) {
        int gr = rowBase + wm + tm * 16 + lm;
        f32x4 a0 = {}, a1 = {};
        if (full || gr < NN) {
          a0 = *(const f32x4*)(A + (size_t)gr * 128 + k0);
          a1 = *(const f32x4*)(A + (size_t)gr * 128 + k0 + 4);
        }
        af[tm] = bf16x8{(__bf16)a0[0], (__bf16)a0[1], (__bf16)a0[2], (__bf16)a0[3],
                        (__bf16)a1[0], (__bf16)a1[1], (__bf16)a1[2], (__bf16)a1[3]};
      }
    } else {
      const __bf16* A = (const __bf16*)Av;
      f32x4 b0 = *(const f32x4*)(bias + k0);
      f32x4 b1 = *(const f32x4*)(bias + k0 + 4);
#pragma unroll
      for (int tm = 0; tm < 4; ++tm) {
        int gr = rowBase + wm + tm * 16 + lm;
        bf16x8 v = {};
        if (full || gr < NN) v = *(const bf16x8*)(A + (size_t)gr * 128 + k0);
        af[tm] = bf16x8{(__bf16)fmaxf((float)v[0] + b0[0], 0.f), (__bf16)fmaxf((float)v[1] + b0[1], 0.f),
                        (__bf16)fmaxf((float)v[2] + b0[2], 0.f), (__bf16)fmaxf((float)v[3] + b0[3], 0.f),
                        (__bf16)fmaxf((float)v[4] + b1[0], 0.f), (__bf16)fmaxf((float)v[5] + b1[1], 0.f),
                        (__bf16)fmaxf((float)v[6] + b1[2], 0.f), (__bf16)fmaxf((float)v[7] + b1[3], 0.f)};
      }
    }
    bf16x8 bfr[NT];
#pragma unroll
    for (int tn = 0; tn < NT; ++tn)
      bfr[tn] = *(const bf16x8*)&lB[(wn + tn * 16 + lm) * LDK + k0];
#pragma unroll
    for (int tm = 0; tm < 4; ++tm)
#pragma unroll
      for (int tn = 0; tn < NT; ++tn)
        acc[tm][tn] = __builtin_amdgcn_mfma_f32_16x16x32_bf16(af[tm], bfr[tn], acc[tm][tn], 0, 0, 0);
  }

  // epilogue: C/D layout col=lane&15, row=(lane>>4)*4+reg; scale by dis[row]
#pragma unroll
  for (int tm = 0; tm < 4; ++tm) {
    int r0 = rowBase + wm + tm * 16 + kg * 4;
#pragma unroll
    for (int tn = 0; tn < NT; ++tn) {
      int c0 = wn + tn * 16 + lm;
#pragma unroll
      for (int r = 0; r < 4; ++r) {
        int gr = r0 + r;
        if (full || gr < NN) {
          float val = acc[tm][tn][r] * dis[gr];
          if constexpr (OUT8) {
            unsigned char* o8 = (unsigned char*)outv;
            unsigned pk = __builtin_amdgcn_cvt_pk_fp8_f32(val, val, 0, 0);
            o8[(size_t)gr * BN + c0] = (unsigned char)(pk & 0xffu);
          } else {
            __bf16* ob = (__bf16*)outv;
            ob[(size_t)gr * BN + c0] = (__bf16)val;
          }
        }
      }
    }
  }
}

// ---------------- grouped pull aggregation (F=128, fp8 payload) ----------------
// Gather wall is bytes-proportional (R1: fetch pinned at the 190 MB compulsory
// floor, rate ~3.6 TB/s regardless of loop structure). fp8 rows = 128 B halve
// the floor. Dequant via hw v_cvt_pk_f32_fp8; masked-fma keeps rounds parallel.

__global__ __launch_bounds__(256) void k_agg128(const unsigned char* __restrict__ tmp8, const int* __restrict__ row_ptr,
                                                const int* __restrict__ csr_src, const float* __restrict__ dis,
                                                __bf16* __restrict__ agg) {
  int wid = (blockIdx.x * 256 + threadIdx.x) >> 6;
  int lane = threadIdx.x & 63;
  if (wid >= NN) return;
  int grp = lane >> 4;   // 0..3
  int fl = lane & 15;    // features [fl*8, fl*8+8)

  int beg = row_ptr[wid];
  int end = row_ptr[wid + 1];

  float acc[8] = {0.f, 0.f, 0.f, 0.f, 0.f, 0.f, 0.f, 0.f};
  if (grp == 0) {
    uint2 sv = *(const uint2*)(tmp8 + (size_t)wid * 128 + fl * 8);
    ACC8_FP8(sv, 1.f);
  }

  for (int base = beg; base < end; base += 64) {
    int cnt = min(64, end - base);
    int sidx = (base + lane < end) ? csr_src[base + lane] : 0;
    int i = 0;
    while (i < cnt) {
      int rem = cnt - i;                  // wave-uniform branch
      if (rem > 16) {                     // one masked round of 32 edges: 8 loads in flight
        uint2 v[8];
#pragma unroll
        for (int u = 0; u < 8; ++u) {
          int s = __shfl(sidx, (i + u * 4 + grp) & 63);
          v[u] = *(const uint2*)(tmp8 + (size_t)s * 128 + fl * 8);
        }
#pragma unroll
        for (int u = 0; u < 8; ++u) {
          float m = (i + u * 4 + grp < cnt) ? 1.f : 0.f;
          ACC8_FP8(v[u], m);
        }
        i += 32;
      } else {                            // one masked round of <=16 edges: 4 loads in flight
        uint2 v[4];
#pragma unroll
        for (int u = 0; u < 4; ++u) {
          int s = __shfl(sidx, (i + u * 4 + grp) & 63);
          v[u] = *(const uint2*)(tmp8 + (size_t)s * 128 + fl * 8);
        }
#pragma unroll
        for (int u = 0; u < 4; ++u) {
          float m = (i + u * 4 + grp < cnt) ? 1.f : 0.f;
          ACC8_FP8(v[u], m);
        }
        i += 16;
      }
    }
  }

#pragma unroll
  for (int t = 0; t < 8; ++t) acc[t] += __shfl_xor(acc[t], 16);
#pragma unroll
  for (int t = 0; t < 8; ++t) acc[t] += __shfl_xor(acc[t], 32);

  if (grp == 0) {
    float d = dis[wid];
    bf16x8 o;
#pragma unroll
    for (int t = 0; t < 8; ++t) o[t] = (__bf16)(acc[t] * d);
    *(bf16x8*)&agg[(size_t)wid * 128 + fl * 8] = o;
  }
}

// ---------------- F=64 grouped aggregation fused with bias+relu+log_softmax ----------------
// Kept bf16: final logits feed log_softmax directly (most error-sensitive) and
// the payload is already half-size.

__global__ __launch_bounds__(256) void k_agg64_final(const __bf16* __restrict__ tmp, const int* __restrict__ row_ptr,
                                                     const int* __restrict__ csr_src, const float* __restrict__ dis,
                                                     const float* __restrict__ b2, float* __restrict__ out) {
  int wid = (blockIdx.x * 256 + threadIdx.x) >> 6;
  int lane = threadIdx.x & 63;
  if (wid >= NN) return;
  int grp = lane >> 3;  // 0..7
  int fl = lane & 7;    // features [fl*8, fl*8+8)

  int beg = row_ptr[wid];
  int end = row_ptr[wid + 1];

  float acc[8];
  {
    bf16x8 sv = {};
    if (grp == 0) sv = *(const bf16x8*)&tmp[(size_t)wid * 64 + fl * 8];
#pragma unroll
    for (int t = 0; t < 8; ++t) acc[t] = (grp == 0) ? (float)sv[t] : 0.f;
  }

  for (int base = beg; base < end; base += 64) {
    int cnt = min(64, end - base);
    int sidx = (base + lane < end) ? csr_src[base + lane] : 0;
    int i = 0;
    while (i < cnt) {
      int rem = cnt - i;                  // wave-uniform
      if (rem > 32) {                     // 64 edges: 8 loads in flight
        bf16x8 v[8];
#pragma unroll
        for (int u = 0; u < 8; ++u) {
          int s = __shfl(sidx, (i + u * 8 + grp) & 63);
          v[u] = *(const bf16x8*)&tmp[(size_t)s * 64 + fl * 8];
        }
#pragma unroll
        for (int u = 0; u < 8; ++u) {
          float m = (i + u * 8 + grp < cnt) ? 1.f : 0.f;
#pragma unroll
          for (int t = 0; t < 8; ++t) acc[t] += m * (float)v[u][t];
        }
        i += 64;
      } else if (rem > 16) {              // 32 edges: 4 loads
        bf16x8 v[4];
#pragma unroll
        for (int u = 0; u < 4; ++u) {
          int s = __shfl(sidx, (i + u * 8 + grp) & 63);
          v[u] = *(const bf16x8*)&tmp[(size_t)s * 64 + fl * 8];
        }
#pragma unroll
        for (int u = 0; u < 4; ++u) {
          float m = (i + u * 8 + grp < cnt) ? 1.f : 0.f;
#pragma unroll
          for (int t = 0; t < 8; ++t) acc[t] += m * (float)v[u][t];
        }
        i += 32;
      } else {                            // <=16 edges: 2 loads
        bf16x8 v[2];
#pragma unroll
        for (int u = 0; u < 2; ++u) {
          int s = __shfl(sidx, (i + u * 8 + grp) & 63);
          v[u] = *(const bf16x8*)&tmp[(size_t)s * 64 + fl * 8];
        }
#pragma unroll
        for (int u = 0; u < 2; ++u) {
          float m = (i + u * 8 + grp < cnt) ? 1.f : 0.f;
#pragma unroll
          for (int t = 0; t < 8; ++t) acc[t] += m * (float)v[u][t];
        }
        i += 16;
      }
    }
  }

#pragma unroll
  for (int t = 0; t < 8; ++t) acc[t] += __shfl_xor(acc[t], 8);
#pragma unroll
  for (int t = 0; t < 8; ++t) acc[t] += __shfl_xor(acc[t], 16);
#pragma unroll
  for (int t = 0; t < 8; ++t) acc[t] += __shfl_xor(acc[t], 32);

  float d = dis[wid];
  float v[8], lm_ = -1e30f;
#pragma unroll
  for (int t = 0; t < 8; ++t) {
    v[t] = fmaxf(acc[t] * d + b2[fl * 8 + t], 0.f);
    lm_ = fmaxf(lm_, v[t]);
  }
#pragma unroll
  for (int off = 32; off > 0; off >>= 1) lm_ = fmaxf(lm_, __shfl_xor(lm_, off));
  float le = 0.f;
#pragma unroll
  for (int t = 0; t < 8; ++t) le += expf(v[t] - lm_);
#pragma unroll
  for (int off = 32; off > 0; off >>= 1) le += __shfl_xor(le, off);
  float logss = logf(le * 0.125f);
  if (grp == 0) {
    float4 o0 = make_float4(v[0] - lm_ - logss, v[1] - lm_ - logss, v[2] - lm_ - logss, v[3] - lm_ - logss);
    float4 o1 = make_float4(v[4] - lm_ - logss, v[5] - lm_ - logss, v[6] - lm_ - logss, v[7] - lm_ - logss);
    *(float4*)&out[(size_t)wid * 64 + fl * 8] = o0;
    *(float4*)&out[(size_t)wid * 64 + fl * 8 + 4] = o1;
  }
}

// ---------------- launch ----------------

extern "C" void kernel_launch(void* const* d_in, const int* in_sizes, int n_in,
                              void* d_out, int out_size, void* d_ws, size_t ws_size,
                              hipStream_t stream) {
  const float* x  = (const float*)d_in[0];
  const int*   ei = (const int*)d_in[1];
  const float* W0 = (const float*)d_in[2];
  const float* b0 = (const float*)d_in[3];
  const float* W1 = (const float*)d_in[4];
  const float* b1 = (const float*)d_in[5];
  const float* W2 = (const float*)d_in[6];
  const float* b2 = (const float*)d_in[7];
  const int* esrc = ei;
  const int* edst = ei + NE;

  char* p = (char*)d_ws;
  auto alloc = [&](size_t bytes) {
    char* q = p;
    p += (bytes + 255) & ~(size_t)255;
    return q;
  };
  float*  dis     = (float*)alloc((size_t)NN * 4);
  int*    row_ptr = (int*)alloc((size_t)(NN + 1) * 4);
  int*    btot    = (int*)alloc(NBK * 4);
  int*    bptr    = (int*)alloc((NBK + 1) * 4);
  __bf16* Wt      = (__bf16*)alloc(40960 * 2);              // 80 KB: Wt0|Wt1|Wt2
  int*    csr_src = (int*)alloc((size_t)NE * 4);            // 6.4 MB
  char*   tmp     = (char*)alloc((size_t)NN * 128 * 2);     // 25.6 MB (fp8 uses 12.8, bf16-F64 uses 12.8)
  unsigned char* tmp8 = (unsigned char*)tmp;
  __bf16* tmp16   = (__bf16*)tmp;
  int*    bucketed  = (int*)tmp;                            // 6.4 MB alias (packed edges)
  int*    bhist     = csr_src;                              // 800 KB alias [bin][block]
  int*    blockbase = csr_src + NBLK * NBK;                 // 800 KB alias [bin][block]

  kW_prep<<<160, 256, 0, stream>>>(W0, W1, W2, Wt);
  k1_hist<<<NBLK, 256, 0, stream>>>(edst, bhist);
  kA2<<<(NBK + 3) / 4, 256, 0, stream>>>(bhist, btot);
  kB_bscan<<<1, 1024, 0, stream>>>(btot, bptr);
  kC2<<<(NBK + 3) / 4, 256, 0, stream>>>(bhist, bptr, blockbase);
  k3_scatter<<<NBLK, 256, 0, stream>>>(esrc, edst, blockbase, bucketed);
  k_degfill<<<NBK, 256, 0, stream>>>(bucketed, bptr, row_ptr, dis, csr_src);

  int gblocks = (NN + 127) / 128;  // 782
  int ablocks = (NN * 64 + 255) / 256;

  k_gemm<128, 0, true><<<gblocks, 256, 0, stream>>>(x, Wt, nullptr, dis, tmp8);
  k_agg128<<<ablocks, 256, 0, stream>>>(tmp8, row_ptr, csr_src, dis, (__bf16*)d_out);

  k_gemm<128, 2, true><<<gblocks, 256, 0, stream>>>(d_out, Wt + 16384, b0, dis, tmp8);
  k_agg128<<<ablocks, 256, 0, stream>>>(tmp8, row_ptr, csr_src, dis, (__bf16*)d_out);

  k_gemm<64, 2, false><<<gblocks, 256, 0, stream>>>(d_out, Wt + 32768, b1, dis, tmp16);
  k_agg64_final<<<ablocks, 256, 0, stream>>>(tmp16, row_ptr, csr_src, dis, b2, (float*)d_out);
}

// Round 3
// 381.216 us; speedup vs baseline: 1.0799x; 1.0020x over previous
//
#include <hip/hip_runtime.h>

#define NN 100000
#define NE 1600000
#define NBK 782   // ceil(NN/128) 128-node buckets
#define NBLK 256  // persistent blocks for counting sort
#define CHUNK ((NE + NBLK - 1) / NBLK)  // 6250

typedef __bf16 bf16x8 __attribute__((ext_vector_type(8)));
typedef float f32x2 __attribute__((ext_vector_type(2)));
typedef float f32x4 __attribute__((ext_vector_type(4)));

// dequant 8 fp8 (uint2), unconditional accumulate into acc[8] (zero-row padded gather)
#define ACC8_FP8(vv)                                                                  \
  {                                                                                   \
    f32x2 p;                                                                          \
    p = __builtin_amdgcn_cvt_pk_f32_fp8((vv).x, 0); acc[0] += p[0]; acc[1] += p[1];   \
    p = __builtin_amdgcn_cvt_pk_f32_fp8((vv).x, 1); acc[2] += p[0]; acc[3] += p[1];   \
    p = __builtin_amdgcn_cvt_pk_f32_fp8((vv).y, 0); acc[4] += p[0]; acc[5] += p[1];   \
    p = __builtin_amdgcn_cvt_pk_f32_fp8((vv).y, 1); acc[6] += p[0]; acc[7] += p[1];   \
  }

// ---------------- W pre-transpose: Wt[n][k] = (bf16)W[k][n], all 3 layers ----------------

__global__ __launch_bounds__(256) void kW_prep(const float* __restrict__ W0, const float* __restrict__ W1,
                                               const float* __restrict__ W2, __bf16* __restrict__ Wt) {
  int i = blockIdx.x * 256 + threadIdx.x;  // 40960 total
  if (i < 16384) {        // W0 128x128, i = k*128+n
    int k = i >> 7, n = i & 127;
    Wt[n * 128 + k] = (__bf16)W0[i];
  } else if (i < 32768) { // W1 128x128
    int j = i - 16384;
    int k = j >> 7, n = j & 127;
    Wt[16384 + n * 128 + k] = (__bf16)W1[j];
  } else if (i < 40960) { // W2 128x64, j = k*64+n
    int j = i - 32768;
    int k = j >> 6, n = j & 63;
    Wt[32768 + n * 128 + k] = (__bf16)W2[j];
  }
}

// ---------------- privatized counting sort by dst-bucket ----------------

__global__ __launch_bounds__(256) void k1_hist(const int* __restrict__ dst, int* __restrict__ bhist) {
  __shared__ int h[NBK];
  int tid = threadIdx.x, b = blockIdx.x;
  for (int i = tid; i < NBK; i += 256) h[i] = 0;
  __syncthreads();
  int base = b * CHUNK, end = min(base + CHUNK, NE);
  for (int e = base + tid; e < end; e += 256) atomicAdd(&h[dst[e] >> 7], 1);
  __syncthreads();
  for (int i = tid; i < NBK; i += 256) bhist[i * NBLK + b] = h[i];
}

__global__ __launch_bounds__(256) void kA2(const int* __restrict__ bhist, int* __restrict__ btot) {
  int w = threadIdx.x >> 6, lane = threadIdx.x & 63;
  int bin = blockIdx.x * 4 + w;
  if (bin >= NBK) return;
  int4 v = *(const int4*)(bhist + bin * NBLK + lane * 4);
  int s = v.x + v.y + v.z + v.w;
#pragma unroll
  for (int off = 32; off > 0; off >>= 1) s += __shfl_xor(s, off);
  if (lane == 0) btot[bin] = s;
}

__global__ __launch_bounds__(1024) void kB_bscan(const int* __restrict__ btot, int* __restrict__ bptr) {
  __shared__ int s[1024];
  int tid = threadIdx.x;
  int v = (tid < NBK) ? btot[tid] : 0;
  s[tid] = v;
  __syncthreads();
  for (int off = 1; off < 1024; off <<= 1) {
    int t = (tid >= off) ? s[tid - off] : 0;
    __syncthreads();
    s[tid] += t;
    __syncthreads();
  }
  if (tid < NBK) bptr[tid + 1] = s[tid];
  if (tid == 0) bptr[0] = 0;
}

__global__ __launch_bounds__(256) void kC2(const int* __restrict__ bhist, const int* __restrict__ bptr,
                                           int* __restrict__ blockbase) {
  int w = threadIdx.x >> 6, lane = threadIdx.x & 63;
  int bin = blockIdx.x * 4 + w;
  if (bin >= NBK) return;
  int4 v = *(const int4*)(bhist + bin * NBLK + lane * 4);
  int ls = v.x + v.y + v.z + v.w;
  int incl = ls;
#pragma unroll
  for (int off = 1; off < 64; off <<= 1) {
    int t = __shfl_up(incl, off);
    if (lane >= off) incl += t;
  }
  int base = bptr[bin] + incl - ls;
  int4 o;
  o.x = base;
  o.y = base + v.x;
  o.z = base + v.x + v.y;
  o.w = base + v.x + v.y + v.z;
  *(int4*)(blockbase + bin * NBLK + lane * 4) = o;
}

__global__ __launch_bounds__(256) void k3_scatter(const int* __restrict__ src, const int* __restrict__ dst,
                                                  const int* __restrict__ blockbase, int* __restrict__ bucketed) {
  __shared__ int cur[NBK];
  int tid = threadIdx.x, b = blockIdx.x;
  for (int i = tid; i < NBK; i += 256) cur[i] = blockbase[i * NBLK + b];
  __syncthreads();
  int base = b * CHUNK, end = min(base + CHUNK, NE);
  for (int e = base + tid; e < end; e += 256) {
    int d = dst[e];
    int pos = atomicAdd(&cur[d >> 7], 1);
    bucketed[pos] = (src[e] << 7) | (d & 127);
  }
}

__global__ __launch_bounds__(256) void k_degfill(const int* __restrict__ bucketed, const int* __restrict__ bptr,
                                                 int* __restrict__ row_ptr, float* __restrict__ dis,
                                                 int* __restrict__ csr_src) {
  __shared__ int deg[128];
  __shared__ int sc[128];
  __shared__ int cur[128];
  int b = blockIdx.x, tid = threadIdx.x;
  int nb0 = b << 7;
  if (tid < 128) deg[tid] = 0;
  __syncthreads();
  int beg = bptr[b], end = bptr[b + 1];
  for (int e = beg + tid; e < end; e += 256) atomicAdd(&deg[bucketed[e] & 127], 1);
  __syncthreads();
  if (tid < 128) sc[tid] = deg[tid];
  __syncthreads();
  for (int off = 1; off < 128; off <<= 1) {
    int t = (tid >= off && tid < 128) ? sc[tid - off] : 0;
    __syncthreads();
    if (tid < 128) sc[tid] += t;
    __syncthreads();
  }
  if (tid < 128) {
    cur[tid] = beg + sc[tid] - deg[tid];
    if (nb0 + tid < NN) {
      row_ptr[nb0 + tid + 1] = beg + sc[tid];
      dis[nb0 + tid] = rsqrtf((float)(deg[tid] + 1));
      if (b == 0 && tid == 0) row_ptr[0] = 0;
    }
  }
  __syncthreads();
  for (int e = beg + tid; e < end; e += 256) {
    int pk = bucketed[e];
    int pos = atomicAdd(&cur[pk & 127], 1);
    csr_src[pos] = pk >> 7;
  }
}

// ---------------- bf16 MFMA GEMM, direct-A-load variant ----------------
// OUT8=true: epilogue quantizes acc*dis to OCP fp8 e4m3 for the gather-bound agg.
// Block 0 also zeroes pad row NN (128 B in both fp8-128 and bf16-64 layouts) so
// the agg kernels can gather it for out-of-range edge slots instead of masking.

template <int BN, int MODE, bool OUT8>
__global__ __launch_bounds__(256) void k_gemm(const void* __restrict__ Av, const __bf16* __restrict__ Wt,
                                              const float* __restrict__ bias, const float* __restrict__ dis,
                                              void* __restrict__ outv) {
  constexpr int LDK = 136;  // 128 + 8 pad: row stride 272 B -> 4-bank rotation
  constexpr int NT = BN / 32;
  constexpr int ROWB = BN * (OUT8 ? 1 : 2);  // bytes per output row
  __shared__ __bf16 lB[BN * LDK];

  const int tid = threadIdx.x;
  const int rowBase = blockIdx.x * 128;
  const int lane = tid & 63;
  const int wid = tid >> 6;
  const int wm = (wid & 1) * 64;
  const int wn = (wid >> 1) * (BN / 2);
  const int lm = lane & 15;
  const int kg = lane >> 4;

  if (blockIdx.x == 0 && tid < ROWB / 16) {  // zero pad row NN for agg gather
    ((uint4*)((char*)outv + (size_t)NN * ROWB))[tid] = make_uint4(0, 0, 0, 0);
  }

  for (int c = tid; c < 16 * BN; c += 256) {
    int n = c >> 4;
    int koff = (c & 15) * 8;
    bf16x8 w = *(const bf16x8*)(Wt + n * 128 + koff);
    *(bf16x8*)&lB[n * LDK + koff] = w;
  }
  __syncthreads();

  f32x4 acc[4][NT] = {};
  const bool full = (rowBase + 128 <= NN);

#pragma unroll 2
  for (int ks = 0; ks < 128; ks += 32) {
    int k0 = ks + kg * 8;
    bf16x8 af[4];
    if constexpr (MODE == 0) {
      const float* A = (const float*)Av;
#pragma unroll
      for (int tm = 0; tm < 4; ++tm) {
        int gr = rowBase + wm + tm * 16 + lm;
        f32x4 a0 = {}, a1 = {};
        if (full || gr < NN) {
          a0 = *(const f32x4*)(A + (size_t)gr * 128 + k0);
          a1 = *(const f32x4*)(A + (size_t)gr * 128 + k0 + 4);
        }
        af[tm] = bf16x8{(__bf16)a0[0], (__bf16)a0[1], (__bf16)a0[2], (__bf16)a0[3],
                        (__bf16)a1[0], (__bf16)a1[1], (__bf16)a1[2], (__bf16)a1[3]};
      }
    } else {
      const __bf16* A = (const __bf16*)Av;
      f32x4 b0 = *(const f32x4*)(bias + k0);
      f32x4 b1 = *(const f32x4*)(bias + k0 + 4);
#pragma unroll
      for (int tm = 0; tm < 4; ++tm) {
        int gr = rowBase + wm + tm * 16 + lm;
        bf16x8 v = {};
        if (full || gr < NN) v = *(const bf16x8*)(A + (size_t)gr * 128 + k0);
        af[tm] = bf16x8{(__bf16)fmaxf((float)v[0] + b0[0], 0.f), (__bf16)fmaxf((float)v[1] + b0[1], 0.f),
                        (__bf16)fmaxf((float)v[2] + b0[2], 0.f), (__bf16)fmaxf((float)v[3] + b0[3], 0.f),
                        (__bf16)fmaxf((float)v[4] + b1[0], 0.f), (__bf16)fmaxf((float)v[5] + b1[1], 0.f),
                        (__bf16)fmaxf((float)v[6] + b1[2], 0.f), (__bf16)fmaxf((float)v[7] + b1[3], 0.f)};
      }
    }
    bf16x8 bfr[NT];
#pragma unroll
    for (int tn = 0; tn < NT; ++tn)
      bfr[tn] = *(const bf16x8*)&lB[(wn + tn * 16 + lm) * LDK + k0];
#pragma unroll
    for (int tm = 0; tm < 4; ++tm)
#pragma unroll
      for (int tn = 0; tn < NT; ++tn)
        acc[tm][tn] = __builtin_amdgcn_mfma_f32_16x16x32_bf16(af[tm], bfr[tn], acc[tm][tn], 0, 0, 0);
  }

  // epilogue: C/D layout col=lane&15, row=(lane>>4)*4+reg; scale by dis[row]
#pragma unroll
  for (int tm = 0; tm < 4; ++tm) {
    int r0 = rowBase + wm + tm * 16 + kg * 4;
#pragma unroll
    for (int tn = 0; tn < NT; ++tn) {
      int c0 = wn + tn * 16 + lm;
#pragma unroll
      for (int r = 0; r < 4; ++r) {
        int gr = r0 + r;
        if (full || gr < NN) {
          float val = acc[tm][tn][r] * dis[gr];
          if constexpr (OUT8) {
            unsigned char* o8 = (unsigned char*)outv;
            unsigned pk = __builtin_amdgcn_cvt_pk_fp8_f32(val, val, 0, 0);
            o8[(size_t)gr * BN + c0] = (unsigned char)(pk & 0xffu);
          } else {
            __bf16* ob = (__bf16*)outv;
            ob[(size_t)gr * BN + c0] = (__bf16)val;
          }
        }
      }
    }
  }
}

// ---------------- grouped pull aggregation (F=128, fp8 payload) ----------------
// Out-of-range slots gather zero row NN -> no masks, pure cvt_pk+add inner loop.

__global__ __launch_bounds__(256) void k_agg128(const unsigned char* __restrict__ tmp8, const int* __restrict__ row_ptr,
                                                const int* __restrict__ csr_src, const float* __restrict__ dis,
                                                __bf16* __restrict__ agg) {
  int wid = (blockIdx.x * 256 + threadIdx.x) >> 6;
  int lane = threadIdx.x & 63;
  if (wid >= NN) return;
  int grp = lane >> 4;   // 0..3
  int fl = lane & 15;    // features [fl*8, fl*8+8)

  int beg = row_ptr[wid];
  int end = row_ptr[wid + 1];

  float acc[8] = {0.f, 0.f, 0.f, 0.f, 0.f, 0.f, 0.f, 0.f};
  if (grp == 0) {
    uint2 sv = *(const uint2*)(tmp8 + (size_t)wid * 128 + fl * 8);
    ACC8_FP8(sv);
  }

  for (int base = beg; base < end; base += 64) {
    int cnt = min(64, end - base);
    int sidx = (base + lane < end) ? csr_src[base + lane] : NN;  // NN = zero row
    int i = 0;
    while (i < cnt) {
      int rem = cnt - i;                  // wave-uniform branch
      if (rem > 16) {                     // 32 edge slots: 8 loads in flight
        uint2 v[8];
#pragma unroll
        for (int u = 0; u < 8; ++u) {
          int s = __shfl(sidx, (i + u * 4 + grp) & 63);
          v[u] = *(const uint2*)(tmp8 + (size_t)s * 128 + fl * 8);
        }
#pragma unroll
        for (int u = 0; u < 8; ++u) ACC8_FP8(v[u]);
        i += 32;
      } else {                            // <=16 edge slots: 4 loads
        uint2 v[4];
#pragma unroll
        for (int u = 0; u < 4; ++u) {
          int s = __shfl(sidx, (i + u * 4 + grp) & 63);
          v[u] = *(const uint2*)(tmp8 + (size_t)s * 128 + fl * 8);
        }
#pragma unroll
        for (int u = 0; u < 4; ++u) ACC8_FP8(v[u]);
        i += 16;
      }
    }
  }

#pragma unroll
  for (int t = 0; t < 8; ++t) acc[t] += __shfl_xor(acc[t], 16);
#pragma unroll
  for (int t = 0; t < 8; ++t) acc[t] += __shfl_xor(acc[t], 32);

  if (grp == 0) {
    float d = dis[wid];
    bf16x8 o;
#pragma unroll
    for (int t = 0; t < 8; ++t) o[t] = (__bf16)(acc[t] * d);
    *(bf16x8*)&agg[(size_t)wid * 128 + fl * 8] = o;
  }
}

// ---------------- F=64 aggregation fused with bias+relu+log_softmax ----------------
// VALU-debloated (R2 was 93% VALUBusy): zero-row gather (no masks), LDS
// transpose-reduce instead of 48-op shuffle reduce, softmax on 1-feature-per-
// lane layout (one __expf/__logf per node, coalesced 4B/lane store).
// Grid is exactly NN waves -> no early return, __syncthreads is uniform.

__global__ __launch_bounds__(256) void k_agg64_final(const __bf16* __restrict__ tmp, const int* __restrict__ row_ptr,
                                                     const int* __restrict__ csr_src, const float* __restrict__ dis,
                                                     const float* __restrict__ b2, float* __restrict__ out) {
  __shared__ float xch[4][8][66];  // stride 66: 2-way banks on write & read, 8B aligned
  int tid = threadIdx.x;
  int wv = tid >> 6;
  int wid = (blockIdx.x * 256 + tid) >> 6;  // one node per wave; grid exact (25000 blocks)
  int lane = tid & 63;
  int grp = lane >> 3;  // 0..7 edge slot within round
  int fl = lane & 7;    // features [fl*8, fl*8+8)

  int beg = row_ptr[wid];
  int end = row_ptr[wid + 1];

  float acc[8];
  {
    bf16x8 sv = {};
    if (grp == 0) sv = *(const bf16x8*)&tmp[(size_t)wid * 64 + fl * 8];
#pragma unroll
    for (int t = 0; t < 8; ++t) acc[t] = (grp == 0) ? (float)sv[t] : 0.f;
  }

  for (int base = beg; base < end; base += 64) {
    int cnt = min(64, end - base);
    int sidx = (base + lane < end) ? csr_src[base + lane] : NN;  // NN = zero row
    int i = 0;
    while (i < cnt) {
      int rem = cnt - i;                  // wave-uniform
      if (rem > 32) {                     // 64 slots: 8 loads
        bf16x8 v[8];
#pragma unroll
        for (int u = 0; u < 8; ++u) {
          int s = __shfl(sidx, (i + u * 8 + grp) & 63);
          v[u] = *(const bf16x8*)&tmp[(size_t)s * 64 + fl * 8];
        }
#pragma unroll
        for (int u = 0; u < 8; ++u)
#pragma unroll
          for (int t = 0; t < 8; ++t) acc[t] += (float)v[u][t];
        i += 64;
      } else if (rem > 16) {              // 32 slots: 4 loads
        bf16x8 v[4];
#pragma unroll
        for (int u = 0; u < 4; ++u) {
          int s = __shfl(sidx, (i + u * 8 + grp) & 63);
          v[u] = *(const bf16x8*)&tmp[(size_t)s * 64 + fl * 8];
        }
#pragma unroll
        for (int u = 0; u < 4; ++u)
#pragma unroll
          for (int t = 0; t < 8; ++t) acc[t] += (float)v[u][t];
        i += 32;
      } else if (rem > 8) {               // 16 slots: 2 loads
        bf16x8 v[2];
#pragma unroll
        for (int u = 0; u < 2; ++u) {
          int s = __shfl(sidx, (i + u * 8 + grp) & 63);
          v[u] = *(const bf16x8*)&tmp[(size_t)s * 64 + fl * 8];
        }
#pragma unroll
        for (int u = 0; u < 2; ++u)
#pragma unroll
          for (int t = 0; t < 8; ++t) acc[t] += (float)v[u][t];
        i += 16;
      } else {                            // <=8 slots: 1 load
        int s = __shfl(sidx, (i + grp) & 63);
        bf16x8 v = *(const bf16x8*)&tmp[(size_t)s * 64 + fl * 8];
#pragma unroll
        for (int t = 0; t < 8; ++t) acc[t] += (float)v[t];
        i += 8;
      }
    }
  }

  // LDS transpose-reduce: partials [grp][feature] -> lane=feature sums 8 partials
  *(f32x2*)&xch[wv][grp][fl * 8 + 0] = f32x2{acc[0], acc[1]};
  *(f32x2*)&xch[wv][grp][fl * 8 + 2] = f32x2{acc[2], acc[3]};
  *(f32x2*)&xch[wv][grp][fl * 8 + 4] = f32x2{acc[4], acc[5]};
  *(f32x2*)&xch[wv][grp][fl * 8 + 6] = f32x2{acc[6], acc[7]};
  __syncthreads();
  float av = 0.f;
#pragma unroll
  for (int g = 0; g < 8; ++g) av += xch[wv][g][lane];

  // softmax over 64 features, one per lane
  float v = fmaxf(av * dis[wid] + b2[lane], 0.f);
  float lm = v;
#pragma unroll
  for (int off = 32; off > 0; off >>= 1) lm = fmaxf(lm, __shfl_xor(lm, off));
  float e = __expf(v - lm);
  float le = e;
#pragma unroll
  for (int off = 32; off > 0; off >>= 1) le += __shfl_xor(le, off);
  out[(size_t)wid * 64 + lane] = v - lm - __logf(le);
}

// ---------------- launch ----------------

extern "C" void kernel_launch(void* const* d_in, const int* in_sizes, int n_in,
                              void* d_out, int out_size, void* d_ws, size_t ws_size,
                              hipStream_t stream) {
  const float* x  = (const float*)d_in[0];
  const int*   ei = (const int*)d_in[1];
  const float* W0 = (const float*)d_in[2];
  const float* b0 = (const float*)d_in[3];
  const float* W1 = (const float*)d_in[4];
  const float* b1 = (const float*)d_in[5];
  const float* W2 = (const float*)d_in[6];
  const float* b2 = (const float*)d_in[7];
  const int* esrc = ei;
  const int* edst = ei + NE;

  char* p = (char*)d_ws;
  auto alloc = [&](size_t bytes) {
    char* q = p;
    p += (bytes + 255) & ~(size_t)255;
    return q;
  };
  float*  dis     = (float*)alloc((size_t)NN * 4);
  int*    row_ptr = (int*)alloc((size_t)(NN + 1) * 4);
  int*    btot    = (int*)alloc(NBK * 4);
  int*    bptr    = (int*)alloc((NBK + 1) * 4);
  __bf16* Wt      = (__bf16*)alloc(40960 * 2);              // 80 KB: Wt0|Wt1|Wt2
  int*    csr_src = (int*)alloc((size_t)NE * 4);            // 6.4 MB
  char*   tmp     = (char*)alloc((size_t)(NN + 1) * 128 * 2); // fp8/bf16 payload + zero row
  unsigned char* tmp8 = (unsigned char*)tmp;
  __bf16* tmp16   = (__bf16*)tmp;
  int*    bucketed  = (int*)tmp;                            // 6.4 MB alias (packed edges)
  int*    bhist     = csr_src;                              // 800 KB alias [bin][block]
  int*    blockbase = csr_src + NBLK * NBK;                 // 800 KB alias [bin][block]

  kW_prep<<<160, 256, 0, stream>>>(W0, W1, W2, Wt);
  k1_hist<<<NBLK, 256, 0, stream>>>(edst, bhist);
  kA2<<<(NBK + 3) / 4, 256, 0, stream>>>(bhist, btot);
  kB_bscan<<<1, 1024, 0, stream>>>(btot, bptr);
  kC2<<<(NBK + 3) / 4, 256, 0, stream>>>(bhist, bptr, blockbase);
  k3_scatter<<<NBLK, 256, 0, stream>>>(esrc, edst, blockbase, bucketed);
  k_degfill<<<NBK, 256, 0, stream>>>(bucketed, bptr, row_ptr, dis, csr_src);

  int gblocks = (NN + 127) / 128;  // 782
  int ablocks = (NN * 64 + 255) / 256;  // 25000: exactly NN waves

  k_gemm<128, 0, true><<<gblocks, 256, 0, stream>>>(x, Wt, nullptr, dis, tmp8);
  k_agg128<<<ablocks, 256, 0, stream>>>(tmp8, row_ptr, csr_src, dis, (__bf16*)d_out);

  k_gemm<128, 2, true><<<gblocks, 256, 0, stream>>>(d_out, Wt + 16384, b0, dis, tmp8);
  k_agg128<<<ablocks, 256, 0, stream>>>(tmp8, row_ptr, csr_src, dis, (__bf16*)d_out);

  k_gemm<64, 2, false><<<gblocks, 256, 0, stream>>>(d_out, Wt + 32768, b1, dis, tmp16);
  k_agg64_final<<<ablocks, 256, 0, stream>>>(tmp16, row_ptr, csr_src, dis, b2, (float*)d_out);
}

// Round 4
// 364.027 us; speedup vs baseline: 1.1309x; 1.0472x over previous
//
#include <hip/hip_runtime.h>

#define NN 100000
#define NE 1600000
#define NBK 782   // ceil(NN/128) 128-node buckets
#define NBLK 256  // persistent blocks for counting sort
#define CHUNK ((NE + NBLK - 1) / NBLK)  // 6250

typedef __bf16 bf16x4 __attribute__((ext_vector_type(4)));
typedef __bf16 bf16x8 __attribute__((ext_vector_type(8)));
typedef float f32x2 __attribute__((ext_vector_type(2)));
typedef float f32x4 __attribute__((ext_vector_type(4)));

// dequant 8 fp8 (uint2), unconditional accumulate into acc[8] (zero-row padded gather)
#define ACC8_FP8(vv)                                                                  \
  {                                                                                   \
    f32x2 p;                                                                          \
    p = __builtin_amdgcn_cvt_pk_f32_fp8((vv).x, 0); acc[0] += p[0]; acc[1] += p[1];   \
    p = __builtin_amdgcn_cvt_pk_f32_fp8((vv).x, 1); acc[2] += p[0]; acc[3] += p[1];   \
    p = __builtin_amdgcn_cvt_pk_f32_fp8((vv).y, 0); acc[4] += p[0]; acc[5] += p[1];   \
    p = __builtin_amdgcn_cvt_pk_f32_fp8((vv).y, 1); acc[6] += p[0]; acc[7] += p[1];   \
  }

// ---------------- W pre-transpose: Wt[n][k] = (bf16)W[k][n], all 3 layers ----------------

__global__ __launch_bounds__(256) void kW_prep(const float* __restrict__ W0, const float* __restrict__ W1,
                                               const float* __restrict__ W2, __bf16* __restrict__ Wt) {
  int i = blockIdx.x * 256 + threadIdx.x;  // 40960 total
  if (i < 16384) {        // W0 128x128, i = k*128+n
    int k = i >> 7, n = i & 127;
    Wt[n * 128 + k] = (__bf16)W0[i];
  } else if (i < 32768) { // W1 128x128
    int j = i - 16384;
    int k = j >> 7, n = j & 127;
    Wt[16384 + n * 128 + k] = (__bf16)W1[j];
  } else if (i < 40960) { // W2 128x64, j = k*64+n
    int j = i - 32768;
    int k = j >> 6, n = j & 63;
    Wt[32768 + n * 128 + k] = (__bf16)W2[j];
  }
}

// ---------------- privatized counting sort by dst-bucket ----------------

__global__ __launch_bounds__(256) void k1_hist(const int* __restrict__ dst, int* __restrict__ bhist) {
  __shared__ int h[NBK];
  int tid = threadIdx.x, b = blockIdx.x;
  for (int i = tid; i < NBK; i += 256) h[i] = 0;
  __syncthreads();
  int base = b * CHUNK, end = min(base + CHUNK, NE);
  for (int e = base + tid; e < end; e += 256) atomicAdd(&h[dst[e] >> 7], 1);
  __syncthreads();
  for (int i = tid; i < NBK; i += 256) bhist[i * NBLK + b] = h[i];
}

__global__ __launch_bounds__(256) void kA2(const int* __restrict__ bhist, int* __restrict__ btot) {
  int w = threadIdx.x >> 6, lane = threadIdx.x & 63;
  int bin = blockIdx.x * 4 + w;
  if (bin >= NBK) return;
  int4 v = *(const int4*)(bhist + bin * NBLK + lane * 4);
  int s = v.x + v.y + v.z + v.w;
#pragma unroll
  for (int off = 32; off > 0; off >>= 1) s += __shfl_xor(s, off);
  if (lane == 0) btot[bin] = s;
}

__global__ __launch_bounds__(1024) void kB_bscan(const int* __restrict__ btot, int* __restrict__ bptr) {
  __shared__ int s[1024];
  int tid = threadIdx.x;
  int v = (tid < NBK) ? btot[tid] : 0;
  s[tid] = v;
  __syncthreads();
  for (int off = 1; off < 1024; off <<= 1) {
    int t = (tid >= off) ? s[tid - off] : 0;
    __syncthreads();
    s[tid] += t;
    __syncthreads();
  }
  if (tid < NBK) bptr[tid + 1] = s[tid];
  if (tid == 0) bptr[0] = 0;
}

__global__ __launch_bounds__(256) void kC2(const int* __restrict__ bhist, const int* __restrict__ bptr,
                                           int* __restrict__ blockbase) {
  int w = threadIdx.x >> 6, lane = threadIdx.x & 63;
  int bin = blockIdx.x * 4 + w;
  if (bin >= NBK) return;
  int4 v = *(const int4*)(bhist + bin * NBLK + lane * 4);
  int ls = v.x + v.y + v.z + v.w;
  int incl = ls;
#pragma unroll
  for (int off = 1; off < 64; off <<= 1) {
    int t = __shfl_up(incl, off);
    if (lane >= off) incl += t;
  }
  int base = bptr[bin] + incl - ls;
  int4 o;
  o.x = base;
  o.y = base + v.x;
  o.z = base + v.x + v.y;
  o.w = base + v.x + v.y + v.z;
  *(int4*)(blockbase + bin * NBLK + lane * 4) = o;
}

__global__ __launch_bounds__(256) void k3_scatter(const int* __restrict__ src, const int* __restrict__ dst,
                                                  const int* __restrict__ blockbase, int* __restrict__ bucketed) {
  __shared__ int cur[NBK];
  int tid = threadIdx.x, b = blockIdx.x;
  for (int i = tid; i < NBK; i += 256) cur[i] = blockbase[i * NBLK + b];
  __syncthreads();
  int base = b * CHUNK, end = min(base + CHUNK, NE);
  for (int e = base + tid; e < end; e += 256) {
    int d = dst[e];
    int pos = atomicAdd(&cur[d >> 7], 1);
    bucketed[pos] = (src[e] << 7) | (d & 127);
  }
}

__global__ __launch_bounds__(256) void k_degfill(const int* __restrict__ bucketed, const int* __restrict__ bptr,
                                                 int* __restrict__ row_ptr, float* __restrict__ dis,
                                                 int* __restrict__ csr_src) {
  __shared__ int deg[128];
  __shared__ int sc[128];
  __shared__ int cur[128];
  int b = blockIdx.x, tid = threadIdx.x;
  int nb0 = b << 7;
  if (tid < 128) deg[tid] = 0;
  __syncthreads();
  int beg = bptr[b], end = bptr[b + 1];
  for (int e = beg + tid; e < end; e += 256) atomicAdd(&deg[bucketed[e] & 127], 1);
  __syncthreads();
  if (tid < 128) sc[tid] = deg[tid];
  __syncthreads();
  for (int off = 1; off < 128; off <<= 1) {
    int t = (tid >= off && tid < 128) ? sc[tid - off] : 0;
    __syncthreads();
    if (tid < 128) sc[tid] += t;
    __syncthreads();
  }
  if (tid < 128) {
    cur[tid] = beg + sc[tid] - deg[tid];
    if (nb0 + tid < NN) {
      row_ptr[nb0 + tid + 1] = beg + sc[tid];
      dis[nb0 + tid] = rsqrtf((float)(deg[tid] + 1));
      if (b == 0 && tid == 0) row_ptr[0] = 0;
    }
  }
  __syncthreads();
  for (int e = beg + tid; e < end; e += 256) {
    int pk = bucketed[e];
    int pos = atomicAdd(&cur[pk & 127], 1);
    csr_src[pos] = pk >> 7;
  }
}

// ---------------- bf16 MFMA GEMM, direct-A-load variant ----------------
// OUT8=true: epilogue quantizes acc*dis to OCP fp8 e4m3 for the gather-bound agg.
// Block 0 also zeroes pad row NN (128 B in both fp8-128 and bf16-64 layouts) so
// the agg kernels can gather it for out-of-range edge slots instead of masking.

template <int BN, int MODE, bool OUT8>
__global__ __launch_bounds__(256) void k_gemm(const void* __restrict__ Av, const __bf16* __restrict__ Wt,
                                              const float* __restrict__ bias, const float* __restrict__ dis,
                                              void* __restrict__ outv) {
  constexpr int LDK = 136;  // 128 + 8 pad: row stride 272 B -> 4-bank rotation
  constexpr int NT = BN / 32;
  constexpr int ROWB = BN * (OUT8 ? 1 : 2);  // bytes per output row
  __shared__ __bf16 lB[BN * LDK];

  const int tid = threadIdx.x;
  const int rowBase = blockIdx.x * 128;
  const int lane = tid & 63;
  const int wid = tid >> 6;
  const int wm = (wid & 1) * 64;
  const int wn = (wid >> 1) * (BN / 2);
  const int lm = lane & 15;
  const int kg = lane >> 4;

  if (blockIdx.x == 0 && tid < ROWB / 16) {  // zero pad row NN for agg gather
    ((uint4*)((char*)outv + (size_t)NN * ROWB))[tid] = make_uint4(0, 0, 0, 0);
  }

  for (int c = tid; c < 16 * BN; c += 256) {
    int n = c >> 4;
    int koff = (c & 15) * 8;
    bf16x8 w = *(const bf16x8*)(Wt + n * 128 + koff);
    *(bf16x8*)&lB[n * LDK + koff] = w;
  }
  __syncthreads();

  f32x4 acc[4][NT] = {};
  const bool full = (rowBase + 128 <= NN);

#pragma unroll 2
  for (int ks = 0; ks < 128; ks += 32) {
    int k0 = ks + kg * 8;
    bf16x8 af[4];
    if constexpr (MODE == 0) {
      const float* A = (const float*)Av;
#pragma unroll
      for (int tm = 0; tm < 4; ++tm) {
        int gr = rowBase + wm + tm * 16 + lm;
        f32x4 a0 = {}, a1 = {};
        if (full || gr < NN) {
          a0 = *(const f32x4*)(A + (size_t)gr * 128 + k0);
          a1 = *(const f32x4*)(A + (size_t)gr * 128 + k0 + 4);
        }
        af[tm] = bf16x8{(__bf16)a0[0], (__bf16)a0[1], (__bf16)a0[2], (__bf16)a0[3],
                        (__bf16)a1[0], (__bf16)a1[1], (__bf16)a1[2], (__bf16)a1[3]};
      }
    } else {
      const __bf16* A = (const __bf16*)Av;
      f32x4 b0 = *(const f32x4*)(bias + k0);
      f32x4 b1 = *(const f32x4*)(bias + k0 + 4);
#pragma unroll
      for (int tm = 0; tm < 4; ++tm) {
        int gr = rowBase + wm + tm * 16 + lm;
        bf16x8 v = {};
        if (full || gr < NN) v = *(const bf16x8*)(A + (size_t)gr * 128 + k0);
        af[tm] = bf16x8{(__bf16)fmaxf((float)v[0] + b0[0], 0.f), (__bf16)fmaxf((float)v[1] + b0[1], 0.f),
                        (__bf16)fmaxf((float)v[2] + b0[2], 0.f), (__bf16)fmaxf((float)v[3] + b0[3], 0.f),
                        (__bf16)fmaxf((float)v[4] + b1[0], 0.f), (__bf16)fmaxf((float)v[5] + b1[1], 0.f),
                        (__bf16)fmaxf((float)v[6] + b1[2], 0.f), (__bf16)fmaxf((float)v[7] + b1[3], 0.f)};
      }
    }
    bf16x8 bfr[NT];
#pragma unroll
    for (int tn = 0; tn < NT; ++tn)
      bfr[tn] = *(const bf16x8*)&lB[(wn + tn * 16 + lm) * LDK + k0];
#pragma unroll
    for (int tm = 0; tm < 4; ++tm)
#pragma unroll
      for (int tn = 0; tn < NT; ++tn)
        acc[tm][tn] = __builtin_amdgcn_mfma_f32_16x16x32_bf16(af[tm], bfr[tn], acc[tm][tn], 0, 0, 0);
  }

  // epilogue: C/D layout col=lane&15, row=(lane>>4)*4+reg; scale by dis[row]
#pragma unroll
  for (int tm = 0; tm < 4; ++tm) {
    int r0 = rowBase + wm + tm * 16 + kg * 4;
#pragma unroll
    for (int tn = 0; tn < NT; ++tn) {
      int c0 = wn + tn * 16 + lm;
#pragma unroll
      for (int r = 0; r < 4; ++r) {
        int gr = r0 + r;
        if (full || gr < NN) {
          float val = acc[tm][tn][r] * dis[gr];
          if constexpr (OUT8) {
            unsigned char* o8 = (unsigned char*)outv;
            unsigned pk = __builtin_amdgcn_cvt_pk_fp8_f32(val, val, 0, 0);
            o8[(size_t)gr * BN + c0] = (unsigned char)(pk & 0xffu);
          } else {
            __bf16* ob = (__bf16*)outv;
            ob[(size_t)gr * BN + c0] = (__bf16)val;
          }
        }
      }
    }
  }
}

// ---------------- grouped pull aggregation (F=128, fp8 payload) ----------------
// Out-of-range slots gather zero row NN -> no masks, pure cvt_pk+add inner loop.

__global__ __launch_bounds__(256) void k_agg128(const unsigned char* __restrict__ tmp8, const int* __restrict__ row_ptr,
                                                const int* __restrict__ csr_src, const float* __restrict__ dis,
                                                __bf16* __restrict__ agg) {
  int wid = (blockIdx.x * 256 + threadIdx.x) >> 6;
  int lane = threadIdx.x & 63;
  if (wid >= NN) return;
  int grp = lane >> 4;   // 0..3
  int fl = lane & 15;    // features [fl*8, fl*8+8)

  int beg = row_ptr[wid];
  int end = row_ptr[wid + 1];

  float acc[8] = {0.f, 0.f, 0.f, 0.f, 0.f, 0.f, 0.f, 0.f};
  if (grp == 0) {
    uint2 sv = *(const uint2*)(tmp8 + (size_t)wid * 128 + fl * 8);
    ACC8_FP8(sv);
  }

  for (int base = beg; base < end; base += 64) {
    int cnt = min(64, end - base);
    int sidx = (base + lane < end) ? csr_src[base + lane] : NN;  // NN = zero row
    int i = 0;
    while (i < cnt) {
      int rem = cnt - i;                  // wave-uniform branch
      if (rem > 16) {                     // 32 edge slots: 8 loads in flight
        uint2 v[8];
#pragma unroll
        for (int u = 0; u < 8; ++u) {
          int s = __shfl(sidx, (i + u * 4 + grp) & 63);
          v[u] = *(const uint2*)(tmp8 + (size_t)s * 128 + fl * 8);
        }
#pragma unroll
        for (int u = 0; u < 8; ++u) ACC8_FP8(v[u]);
        i += 32;
      } else {                            // <=16 edge slots: 4 loads
        uint2 v[4];
#pragma unroll
        for (int u = 0; u < 4; ++u) {
          int s = __shfl(sidx, (i + u * 4 + grp) & 63);
          v[u] = *(const uint2*)(tmp8 + (size_t)s * 128 + fl * 8);
        }
#pragma unroll
        for (int u = 0; u < 4; ++u) ACC8_FP8(v[u]);
        i += 16;
      }
    }
  }

#pragma unroll
  for (int t = 0; t < 8; ++t) acc[t] += __shfl_xor(acc[t], 16);
#pragma unroll
  for (int t = 0; t < 8; ++t) acc[t] += __shfl_xor(acc[t], 32);

  if (grp == 0) {
    float d = dis[wid];
    bf16x8 o;
#pragma unroll
    for (int t = 0; t < 8; ++t) o[t] = (__bf16)(acc[t] * d);
    *(bf16x8*)&agg[(size_t)wid * 128 + fl * 8] = o;
  }
}

// ---------------- F=64 aggregation fused with bias+relu+log_softmax ----------------
// R3 showed this kernel is gather-concurrency-bound, not VALU-bound. Reshaped to
// the agg128 pattern (16 lanes/row x 8 B/lane, 4 groups, 4-8 loads in flight) and
// dropped the LDS transpose (shuffle reduce) so LDS=0 and occupancy recovers.
// Softmax on 4-features-per-lane layout; coalesced f32x4 store by lanes 0-15.

__global__ __launch_bounds__(256) void k_agg64_final(const __bf16* __restrict__ tmp, const int* __restrict__ row_ptr,
                                                     const int* __restrict__ csr_src, const float* __restrict__ dis,
                                                     const float* __restrict__ b2, float* __restrict__ out) {
  int wid = (blockIdx.x * 256 + threadIdx.x) >> 6;  // one node per wave; grid exact
  int lane = threadIdx.x & 63;
  int grp = lane >> 4;   // 0..3 edge slot within round
  int fl = lane & 15;    // features [fl*4, fl*4+4)

  int beg = row_ptr[wid];
  int end = row_ptr[wid + 1];

  float acc[4] = {0.f, 0.f, 0.f, 0.f};
  if (grp == 0) {
    bf16x4 sv = *(const bf16x4*)&tmp[(size_t)wid * 64 + fl * 4];
#pragma unroll
    for (int t = 0; t < 4; ++t) acc[t] = (float)sv[t];
  }

  for (int base = beg; base < end; base += 64) {
    int cnt = min(64, end - base);
    int sidx = (base + lane < end) ? csr_src[base + lane] : NN;  // NN = zero row
    int i = 0;
    while (i < cnt) {
      int rem = cnt - i;                  // wave-uniform branch
      if (rem > 16) {                     // 32 edge slots: 8 loads in flight
        bf16x4 v[8];
#pragma unroll
        for (int u = 0; u < 8; ++u) {
          int s = __shfl(sidx, (i + u * 4 + grp) & 63);
          v[u] = *(const bf16x4*)&tmp[(size_t)s * 64 + fl * 4];
        }
#pragma unroll
        for (int u = 0; u < 8; ++u)
#pragma unroll
          for (int t = 0; t < 4; ++t) acc[t] += (float)v[u][t];
        i += 32;
      } else {                            // <=16 edge slots: 4 loads
        bf16x4 v[4];
#pragma unroll
        for (int u = 0; u < 4; ++u) {
          int s = __shfl(sidx, (i + u * 4 + grp) & 63);
          v[u] = *(const bf16x4*)&tmp[(size_t)s * 64 + fl * 4];
        }
#pragma unroll
        for (int u = 0; u < 4; ++u)
#pragma unroll
          for (int t = 0; t < 4; ++t) acc[t] += (float)v[u][t];
        i += 16;
      }
    }
  }

  // reduce over the 4 groups: every lane ends with full sums for its 4 features
#pragma unroll
  for (int t = 0; t < 4; ++t) acc[t] += __shfl_xor(acc[t], 16);
#pragma unroll
  for (int t = 0; t < 4; ++t) acc[t] += __shfl_xor(acc[t], 32);

  // bias + relu + log_softmax over 64 features (4 per lane, 16-lane groups)
  float d = dis[wid];
  float v[4], lm = -1e30f;
#pragma unroll
  for (int t = 0; t < 4; ++t) {
    v[t] = fmaxf(acc[t] * d + b2[fl * 4 + t], 0.f);
    lm = fmaxf(lm, v[t]);
  }
#pragma unroll
  for (int off = 8; off > 0; off >>= 1) lm = fmaxf(lm, __shfl_xor(lm, off));
  float le = 0.f;
#pragma unroll
  for (int t = 0; t < 4; ++t) le += __expf(v[t] - lm);
#pragma unroll
  for (int off = 8; off > 0; off >>= 1) le += __shfl_xor(le, off);
  float ls = lm + __logf(le);
  if (grp == 0) {
    f32x4 o = {v[0] - ls, v[1] - ls, v[2] - ls, v[3] - ls};
    *(f32x4*)&out[(size_t)wid * 64 + fl * 4] = o;
  }
}

// ---------------- launch ----------------

extern "C" void kernel_launch(void* const* d_in, const int* in_sizes, int n_in,
                              void* d_out, int out_size, void* d_ws, size_t ws_size,
                              hipStream_t stream) {
  const float* x  = (const float*)d_in[0];
  const int*   ei = (const int*)d_in[1];
  const float* W0 = (const float*)d_in[2];
  const float* b0 = (const float*)d_in[3];
  const float* W1 = (const float*)d_in[4];
  const float* b1 = (const float*)d_in[5];
  const float* W2 = (const float*)d_in[6];
  const float* b2 = (const float*)d_in[7];
  const int* esrc = ei;
  const int* edst = ei + NE;

  char* p = (char*)d_ws;
  auto alloc = [&](size_t bytes) {
    char* q = p;
    p += (bytes + 255) & ~(size_t)255;
    return q;
  };
  float*  dis     = (float*)alloc((size_t)NN * 4);
  int*    row_ptr = (int*)alloc((size_t)(NN + 1) * 4);
  int*    btot    = (int*)alloc(NBK * 4);
  int*    bptr    = (int*)alloc((NBK + 1) * 4);
  __bf16* Wt      = (__bf16*)alloc(40960 * 2);              // 80 KB: Wt0|Wt1|Wt2
  int*    csr_src = (int*)alloc((size_t)NE * 4);            // 6.4 MB
  char*   tmp     = (char*)alloc((size_t)(NN + 1) * 128 * 2); // fp8/bf16 payload + zero row
  unsigned char* tmp8 = (unsigned char*)tmp;
  __bf16* tmp16   = (__bf16*)tmp;
  int*    bucketed  = (int*)tmp;                            // 6.4 MB alias (packed edges)
  int*    bhist     = csr_src;                              // 800 KB alias [bin][block]
  int*    blockbase = csr_src + NBLK * NBK;                 // 800 KB alias [bin][block]

  kW_prep<<<160, 256, 0, stream>>>(W0, W1, W2, Wt);
  k1_hist<<<NBLK, 256, 0, stream>>>(edst, bhist);
  kA2<<<(NBK + 3) / 4, 256, 0, stream>>>(bhist, btot);
  kB_bscan<<<1, 1024, 0, stream>>>(btot, bptr);
  kC2<<<(NBK + 3) / 4, 256, 0, stream>>>(bhist, bptr, blockbase);
  k3_scatter<<<NBLK, 256, 0, stream>>>(esrc, edst, blockbase, bucketed);
  k_degfill<<<NBK, 256, 0, stream>>>(bucketed, bptr, row_ptr, dis, csr_src);

  int gblocks = (NN + 127) / 128;  // 782
  int ablocks = (NN * 64 + 255) / 256;  // 25000: exactly NN waves

  k_gemm<128, 0, true><<<gblocks, 256, 0, stream>>>(x, Wt, nullptr, dis, tmp8);
  k_agg128<<<ablocks, 256, 0, stream>>>(tmp8, row_ptr, csr_src, dis, (__bf16*)d_out);

  k_gemm<128, 2, true><<<gblocks, 256, 0, stream>>>(d_out, Wt + 16384, b0, dis, tmp8);
  k_agg128<<<ablocks, 256, 0, stream>>>(tmp8, row_ptr, csr_src, dis, (__bf16*)d_out);

  k_gemm<64, 2, false><<<gblocks, 256, 0, stream>>>(d_out, Wt + 32768, b1, dis, tmp16);
  k_agg64_final<<<ablocks, 256, 0, stream>>>(tmp16, row_ptr, csr_src, dis, b2, (float*)d_out);
}